// Round 10
// baseline (144.231 us; speedup 1.0000x reference)
//
#include <hip/hip_runtime.h>

constexpr int IN_DIM  = 256;
constexpr int OUT_DIM = 64;
constexpr int NPB     = 128;          // nodes per bucket (dst >> 7)
constexpr int IPT     = 16;           // edges per thread in part role

typedef __attribute__((ext_vector_type(8))) short bf16x8;
typedef __attribute__((ext_vector_type(4))) float f32x4;

__device__ __forceinline__ void gload_lds16(const void* g, void* l) {
    __builtin_amdgcn_global_load_lds(
        (const __attribute__((address_space(1))) void*)g,
        (__attribute__((address_space(3))) void*)l, 16, 0, 0);
}

// ---- K1: W fragment precompute + zero cnt[] --------------------------------
__global__ __launch_bounds__(64) void wfrag_k(const float* __restrict__ W,
                                              bf16x8* __restrict__ fragH,
                                              bf16x8* __restrict__ fragL,
                                              int* __restrict__ cnt) {
    const int gid = blockIdx.x * 64 + threadIdx.x;
    if (gid < 1024) cnt[gid] = 0;

    const int kt = blockIdx.x >> 2;
    const int nt = blockIdx.x & 3;
    const int l  = threadIdx.x;
    const int col = nt * 16 + (l & 15);
    const int k0  = kt * 32 + (l >> 4) * 8;
    bf16x8 h, lo;
#pragma unroll
    for (int j = 0; j < 8; ++j) {
        float f = W[(size_t)(k0 + j) * OUT_DIM + col];
        unsigned u = __float_as_uint(f);
        h[j] = (short)(u >> 16);
        float r = f - __uint_as_float(u & 0xFFFF0000u);
        lo[j] = (short)(__float_as_uint(r) >> 16);
    }
    fragH[blockIdx.x * 64 + l] = h;
    fragL[blockIdx.x * 64 + l] = lo;
}

// ---- K2: bucket histogram --------------------------------------------------
__global__ __launch_bounds__(256) void histb_k(const int* __restrict__ edst,
                                               int* __restrict__ cnt, int E) {
    __shared__ int h[1024];
    int t = threadIdx.x;
#pragma unroll
    for (int i = t; i < 1024; i += 256) h[i] = 0;
    __syncthreads();
    const int n4 = E >> 2;
    for (int i = blockIdx.x * 256 + t; i < n4; i += gridDim.x * 256) {
        int4 d4 = reinterpret_cast<const int4*>(edst)[i];
        atomicAdd(&h[d4.x >> 7], 1);
        atomicAdd(&h[d4.y >> 7], 1);
        atomicAdd(&h[d4.z >> 7], 1);
        atomicAdd(&h[d4.w >> 7], 1);
    }
    if (blockIdx.x == 0)
        for (int e = (n4 << 2) + t; e < E; e += 256)
            atomicAdd(&h[edst[e] >> 7], 1);
    __syncthreads();
    for (int i = t; i < 1024; i += 256)
        if (h[i]) atomicAdd(&cnt[i], h[i]);
}

// ---- K3: exclusive scan of bucket counts -----------------------------------
__global__ __launch_bounds__(1024) void scanb_k(const int* __restrict__ cnt,
                                                int* __restrict__ base,
                                                int* __restrict__ cursor,
                                                int NB, int E) {
    __shared__ int s[1024];
    int t = threadIdx.x;
    int v = (t < NB) ? cnt[t] : 0;
    s[t] = v;
    __syncthreads();
#pragma unroll
    for (int o = 1; o < 1024; o <<= 1) {
        int a = (t >= o) ? s[t - o] : 0;
        __syncthreads();
        s[t] += a;
        __syncthreads();
    }
    if (t < NB) { base[t] = s[t] - v; cursor[t] = s[t] - v; }
    if (t == 0) base[NB] = E;
}

// ---- K4: union — blocks [0,GB2) = LDS-staged MFMA GEMM, rest = partition ---
// GEMM: 64 rows/block staged into 64KB LDS via global_load_lds (no VGPR
// round-trip, vmcnt-counted). XOR-swizzle (rule #21, both sides): LDS dest
// linear, per-lane GLOBAL source pre-swizzled slot = lane ^ (row&7); reads
// at byte ^ ((row&7)<<4) -> 2-way bank alias (free). One wave = 16 rows.
__global__ __launch_bounds__(256, 2) void gemm_part_k(
        const float* __restrict__ x,
        const bf16x8* __restrict__ fragH, const bf16x8* __restrict__ fragL,
        unsigned short* __restrict__ xw,
        const int* __restrict__ esrc, const int* __restrict__ edst,
        const float* __restrict__ ew,
        int* __restrict__ cursor, int2* __restrict__ rec,
        int N, int E, int GB2, int NB) {
    __shared__ char smem[65536];
    const int bid = blockIdx.x;
    const int tid = threadIdx.x;

    if (bid >= GB2) {                       // ---- partition role ----
        int* h  = (int*)smem;               // [1024]
        int* bb = (int*)smem + 1024;        // [1024]
#pragma unroll
        for (int i = tid; i < 1024; i += 256) h[i] = 0;
        __syncthreads();
        const int e0 = (bid - GB2) * (256 * IPT);
        int br[IPT];
#pragma unroll
        for (int i = 0; i < IPT; ++i) {
            int e = e0 + i * 256 + tid;
            br[i] = -1;
            if (e < E) {
                int d = edst[e];
                int b = d >> 7;
                int r = atomicAdd(&h[b], 1);      // local rank < 4096
                br[i] = (b << 19) | ((d & 127) << 12) | r;
            }
        }
        __syncthreads();
        for (int i = tid; i < NB; i += 256) {
            int c = h[i];
            bb[i] = c ? atomicAdd(&cursor[i], c) : 0;
        }
        __syncthreads();
#pragma unroll
        for (int i = 0; i < IPT; ++i) {
            if (br[i] >= 0) {
                int e = e0 + i * 256 + tid;
                int b = br[i] >> 19;
                int dlow = (br[i] >> 12) & 127;
                int r = br[i] & 0xFFF;
                rec[bb[b] + r] = make_int2(esrc[e] | (dlow << 17),
                                           __float_as_int(ew[e]));
            }
        }
        return;
    }

    // ---- GEMM role ----
    const int lane = tid & 63;
    const int wave = tid >> 6;
    const int row0 = bid * 64;
    float* xs = (float*)smem;               // [64][256] f32, physical/linear

    // stage: wave w covers physical rows w*16..w*16+15, one 1KB row per step
#pragma unroll
    for (int i = 0; i < 16; ++i) {
        const int rp = wave * 16 + i;
        int gr = row0 + rp;
        if (gr > N - 1) gr = N - 1;         // clamp (tail block only)
        const int slot = lane ^ (rp & 7);   // inverse-swizzled 16B slot
        gload_lds16(x + (size_t)gr * IN_DIM + slot * 4,
                    (char*)xs + rp * 1024);
    }
    asm volatile("s_waitcnt vmcnt(0)" ::: "memory");
    __syncthreads();

    const int rlo = lane & 15;
    const int khi = lane >> 4;
    const char* xrow = (const char*)xs + (wave * 16 + rlo) * 1024;
    const int sw = (rlo & 7) << 4;

    f32x4 acc[4];
#pragma unroll
    for (int nt = 0; nt < 4; ++nt) acc[nt] = (f32x4){0.f, 0.f, 0.f, 0.f};

#pragma unroll
    for (int kt = 0; kt < 8; ++kt) {
        bf16x8 bh[4], bl[4];
#pragma unroll
        for (int nt = 0; nt < 4; ++nt) {
            bh[nt] = fragH[(kt * 4 + nt) * 64 + lane];   // L2-hot
            bl[nt] = fragL[(kt * 4 + nt) * 64 + lane];
        }
        const int L0 = kt * 128 + khi * 32;
        float4 a0 = *reinterpret_cast<const float4*>(xrow + (L0 ^ sw));
        float4 a1 = *reinterpret_cast<const float4*>(xrow + ((L0 + 16) ^ sw));
        float f0[8] = {a0.x, a0.y, a0.z, a0.w, a1.x, a1.y, a1.z, a1.w};
        bf16x8 ah, al;
#pragma unroll
        for (int j = 0; j < 8; ++j) {
            unsigned u = __float_as_uint(f0[j]);
            ah[j] = (short)(u >> 16);
            float r = f0[j] - __uint_as_float(u & 0xFFFF0000u);
            al[j] = (short)(__float_as_uint(r) >> 16);
        }
#pragma unroll
        for (int nt = 0; nt < 4; ++nt) {
            acc[nt] = __builtin_amdgcn_mfma_f32_16x16x32_bf16(
                ah, bh[nt], acc[nt], 0, 0, 0);
            acc[nt] = __builtin_amdgcn_mfma_f32_16x16x32_bf16(
                ah, bl[nt], acc[nt], 0, 0, 0);
            acc[nt] = __builtin_amdgcn_mfma_f32_16x16x32_bf16(
                al, bh[nt], acc[nt], 0, 0, 0);
        }
    }

    // C/D: col = nt*16 + rlo, row = wave*16 + khi*4 + i; store bf16 RTN
#pragma unroll
    for (int nt = 0; nt < 4; ++nt)
#pragma unroll
        for (int i = 0; i < 4; ++i) {
            int row = row0 + wave * 16 + khi * 4 + i;
            int col = nt * 16 + rlo;
            if (row < N) {
                unsigned u = __float_as_uint(acc[nt][i]);
                u += 0x7fffu + ((u >> 16) & 1u);
                xw[(size_t)row * OUT_DIM + col] = (unsigned short)(u >> 16);
            }
        }
}

// ---- K5: finalize — per-bucket counting sort -> node-ordered val[] + off[] -
__global__ __launch_bounds__(256) void finalize_k(const int2* __restrict__ rec,
                                                  const int* __restrict__ base,
                                                  int2* __restrict__ val,
                                                  int* __restrict__ off,
                                                  int N, int NB) {
    __shared__ int cnt[NPB];
    __shared__ int sc[NPB];
    __shared__ int cur[NPB];
    const int t = threadIdx.x;
    const int b = blockIdx.x;
    const int s = base[b], e = base[b + 1];

    if (t < NPB) cnt[t] = 0;
    __syncthreads();
    for (int i = s + t; i < e; i += 256)
        atomicAdd(&cnt[(rec[i].x >> 17) & 127], 1);
    __syncthreads();

    if (t < NPB) sc[t] = cnt[t];
    __syncthreads();
#pragma unroll
    for (int o = 1; o < NPB; o <<= 1) {
        int a = 0;
        if (t < NPB && t >= o) a = sc[t - o];
        __syncthreads();
        if (t < NPB) sc[t] += a;
        __syncthreads();
    }
    if (t < NPB) {
        int excl = sc[t] - cnt[t];
        cur[t] = excl;
        int node = b * NPB + t;
        if (node < N) off[node] = s + excl;
    }
    if (b == NB - 1 && t == 0) off[N] = e;
    __syncthreads();

    for (int i = s + t; i < e; i += 256) {
        int2 r = rec[i];
        int dl = (r.x >> 17) & 127;
        int slot = s + atomicAdd(&cur[dl], 1);
        val[slot] = make_int2(r.x & 0x1FFFF, r.y);
    }
}

// ---- K6: gather — wave = 1 node, 16 edges in flight, fused ReLU ------------
__global__ __launch_bounds__(256) void gather_k(const unsigned short* __restrict__ xw,
                                                const int2* __restrict__ val,
                                                const int* __restrict__ off,
                                                float* __restrict__ out, int N) {
    int d = blockIdx.x * 4 + (threadIdx.x >> 6);
    if (d >= N) return;
    const int lane = threadIdx.x & 63;
    const int g = lane >> 3, s = lane & 7;
    const int b = off[d], e = off[d + 1];

    float acc[8];
#pragma unroll
    for (int j = 0; j < 8; ++j) acc[j] = 0.f;

    for (int i = b; i < e; i += 16) {
        int idx0 = i + g;
        int idx1 = i + g + 8;
        int2 r0 = val[min(idx0, e - 1)];
        int2 r1 = val[min(idx1, e - 1)];
        float w0 = (idx0 < e) ? __int_as_float(r0.y) : 0.f;
        float w1 = (idx1 < e) ? __int_as_float(r1.y) : 0.f;
        int4 row0 = *reinterpret_cast<const int4*>(
            xw + (size_t)r0.x * OUT_DIM + s * 8);
        int4 row1 = *reinterpret_cast<const int4*>(
            xw + (size_t)r1.x * OUT_DIM + s * 8);
        unsigned a0 = (unsigned)row0.x, a1 = (unsigned)row0.y;
        unsigned a2 = (unsigned)row0.z, a3 = (unsigned)row0.w;
        acc[0] += w0 * __uint_as_float(a0 << 16);
        acc[1] += w0 * __uint_as_float(a0 & 0xFFFF0000u);
        acc[2] += w0 * __uint_as_float(a1 << 16);
        acc[3] += w0 * __uint_as_float(a1 & 0xFFFF0000u);
        acc[4] += w0 * __uint_as_float(a2 << 16);
        acc[5] += w0 * __uint_as_float(a2 & 0xFFFF0000u);
        acc[6] += w0 * __uint_as_float(a3 << 16);
        acc[7] += w0 * __uint_as_float(a3 & 0xFFFF0000u);
        unsigned b0 = (unsigned)row1.x, b1 = (unsigned)row1.y;
        unsigned b2 = (unsigned)row1.z, b3 = (unsigned)row1.w;
        acc[0] += w1 * __uint_as_float(b0 << 16);
        acc[1] += w1 * __uint_as_float(b0 & 0xFFFF0000u);
        acc[2] += w1 * __uint_as_float(b1 << 16);
        acc[3] += w1 * __uint_as_float(b1 & 0xFFFF0000u);
        acc[4] += w1 * __uint_as_float(b2 << 16);
        acc[5] += w1 * __uint_as_float(b2 & 0xFFFF0000u);
        acc[6] += w1 * __uint_as_float(b3 << 16);
        acc[7] += w1 * __uint_as_float(b3 & 0xFFFF0000u);
    }

#pragma unroll
    for (int m = 8; m < 64; m <<= 1)
#pragma unroll
        for (int j = 0; j < 8; ++j)
            acc[j] += __shfl_xor(acc[j], m);

    if (g == 0) {
        float4 v0 = make_float4(fmaxf(acc[0], 0.f), fmaxf(acc[1], 0.f),
                                fmaxf(acc[2], 0.f), fmaxf(acc[3], 0.f));
        float4 v1 = make_float4(fmaxf(acc[4], 0.f), fmaxf(acc[5], 0.f),
                                fmaxf(acc[6], 0.f), fmaxf(acc[7], 0.f));
        float4* op = reinterpret_cast<float4*>(out + (size_t)d * OUT_DIM + s * 8);
        op[0] = v0;
        op[1] = v1;
    }
}

extern "C" void kernel_launch(void* const* d_in, const int* in_sizes, int n_in,
                              void* d_out, int out_size, void* d_ws, size_t ws_size,
                              hipStream_t stream) {
    const float* x    = (const float*)d_in[0];
    const float* W    = (const float*)d_in[1];
    const int*   esrc = (const int*)d_in[2];
    const int*   edst = (const int*)d_in[3];
    const float* ew   = (const float*)d_in[4];
    float* out = (float*)d_out;

    const int N   = in_sizes[0] / IN_DIM;    // 100000
    const int E   = in_sizes[2];             // 1600000
    const int NB  = (N + NPB - 1) / NPB;     // 782
    const int GB2 = (N + 63) / 64;           // gemm blocks = 1563
    const int PB  = (E + 256 * IPT - 1) / (256 * IPT);   // 391

    char* ws = (char*)d_ws;
    size_t o = 0;
    bf16x8* fragH = (bf16x8*)(ws + o);  o += 32 * 64 * 16;
    bf16x8* fragL = (bf16x8*)(ws + o);  o += 32 * 64 * 16;
    unsigned short* xw = (unsigned short*)(ws + o);
    o += (size_t)N * OUT_DIM * 2;            // 12.8 MB
    int2* rec  = (int2*)(ws + o);       o += (size_t)E * 8;   // 12.8 MB
    int2* val  = (int2*)(ws + o);       o += (size_t)E * 8;   // 12.8 MB
    int* cnt   = (int*)(ws + o);        o += 1024 * 4;
    int* base  = (int*)(ws + o);        o += 1025 * 4;
    int* cursor = (int*)(ws + o);       o += 1024 * 4;
    int* off   = (int*)(ws + o);        o += (size_t)(N + 1) * 4;

    wfrag_k<<<32, 64, 0, stream>>>(W, fragH, fragL, cnt);
    histb_k<<<512, 256, 0, stream>>>(edst, cnt, E);
    scanb_k<<<1, 1024, 0, stream>>>(cnt, base, cursor, NB, E);
    gemm_part_k<<<GB2 + PB, 256, 0, stream>>>(x, fragH, fragL, xw,
                                              esrc, edst, ew, cursor, rec,
                                              N, E, GB2, NB);
    finalize_k<<<NB, 256, 0, stream>>>(rec, base, val, off, N, NB);
    gather_k<<<(N + 3) / 4, 256, 0, stream>>>(xw, val, off, out, N);
}

// Round 11
// 127.791 us; speedup vs baseline: 1.1286x; 1.1286x over previous
//
#include <hip/hip_runtime.h>

constexpr int IN_DIM  = 256;
constexpr int OUT_DIM = 64;
constexpr int NPB     = 128;          // nodes per bucket (dst >> 7)
constexpr int IPT     = 16;           // edges per thread in part_k
constexpr int CAP     = 3072;         // LDS bucket capacity in fingather

typedef __attribute__((ext_vector_type(8))) short bf16x8;
typedef __attribute__((ext_vector_type(4))) float f32x4;

__device__ __forceinline__ void gload_lds16(const void* g, void* l) {
    __builtin_amdgcn_global_load_lds(
        (const __attribute__((address_space(1))) void*)g,
        (__attribute__((address_space(3))) void*)l, 16, 0, 0);
}

// ---- K1: W fragment precompute + zero cnt[] --------------------------------
__global__ __launch_bounds__(64) void wfrag_k(const float* __restrict__ W,
                                              bf16x8* __restrict__ fragH,
                                              bf16x8* __restrict__ fragL,
                                              int* __restrict__ cnt) {
    const int gid = blockIdx.x * 64 + threadIdx.x;
    if (gid < 1024) cnt[gid] = 0;

    const int kt = blockIdx.x >> 2;
    const int nt = blockIdx.x & 3;
    const int l  = threadIdx.x;
    const int col = nt * 16 + (l & 15);
    const int k0  = kt * 32 + (l >> 4) * 8;
    bf16x8 h, lo;
#pragma unroll
    for (int j = 0; j < 8; ++j) {
        float f = W[(size_t)(k0 + j) * OUT_DIM + col];
        unsigned u = __float_as_uint(f);
        h[j] = (short)(u >> 16);
        float r = f - __uint_as_float(u & 0xFFFF0000u);
        lo[j] = (short)(__float_as_uint(r) >> 16);
    }
    fragH[blockIdx.x * 64 + l] = h;
    fragL[blockIdx.x * 64 + l] = lo;
}

// ---- K2: union — [0,GB) = pipelined LDS GEMM, [GB,GB+HB) = histogram -------
// GEMM: 128 rows/block = 8 tiles x 16 rows, double-buffered 2x16KB LDS.
// Wave w owns output col-tile nt=w; its 16 W-fragments live in registers
// (loaded once). Inner loop: stage tile t+1 via global_load_lds (VGPR-free)
// || compute tile t from LDS. One barrier per tile (compiler drains vmcnt).
// XOR swizzle both sides (rule #21): stage src slot = lane ^ (rit&7),
// read addr ^ ((rlo&7)<<4).
__global__ __launch_bounds__(256, 4) void gemm_hist_k(
        const float* __restrict__ x,
        const bf16x8* __restrict__ fragH, const bf16x8* __restrict__ fragL,
        unsigned short* __restrict__ xw,
        const int* __restrict__ edst, int* __restrict__ cnt,
        int N, int E, int GB, int HB) {
    __shared__ char smem[32768];
    const int bid = blockIdx.x;
    const int tid = threadIdx.x;

    if (bid >= GB) {                        // ---- histogram role ----
        int* h = (int*)smem;
        for (int i = tid; i < 1024; i += 256) h[i] = 0;
        __syncthreads();
        const int hb = bid - GB;
        const int n4 = E >> 2;
        for (int i = hb * 256 + tid; i < n4; i += HB * 256) {
            int4 d4 = reinterpret_cast<const int4*>(edst)[i];
            atomicAdd(&h[d4.x >> 7], 1);
            atomicAdd(&h[d4.y >> 7], 1);
            atomicAdd(&h[d4.z >> 7], 1);
            atomicAdd(&h[d4.w >> 7], 1);
        }
        if (hb == 0)
            for (int e = (n4 << 2) + tid; e < E; e += 256)
                atomicAdd(&h[edst[e] >> 7], 1);
        __syncthreads();
        for (int i = tid; i < 1024; i += 256)
            if (h[i]) atomicAdd(&cnt[i], h[i]);
        return;
    }

    // ---- GEMM role ----
    const int lane = tid & 63;
    const int wid  = tid >> 6;              // wave id == my nt
    const int row0 = bid * 128;
    const int rlo = lane & 15, khi = lane >> 4;

    bf16x8 FH[8], FL[8];                    // W frags for nt=wid, all kt
#pragma unroll
    for (int kt = 0; kt < 8; ++kt) {
        FH[kt] = fragH[(kt * 4 + wid) * 64 + lane];
        FL[kt] = fragL[(kt * 4 + wid) * 64 + lane];
    }

    float* buf0 = (float*)smem;             // 16 rows x 1KB
    float* buf1 = (float*)(smem + 16384);

    auto STAGE = [&](float* buf, int tile) {
#pragma unroll
        for (int i = 0; i < 4; ++i) {
            int rit = i * 4 + wid;          // physical LDS row 0..15
            int gr = row0 + tile * 16 + rit;
            if (gr > N - 1) gr = N - 1;     // tail clamp (dup data, masked)
            int slot = lane ^ (rit & 7);    // inverse-swizzled 16B slot
            gload_lds16(x + (size_t)gr * IN_DIM + slot * 4,
                        (char*)buf + rit * 1024);
        }
    };

    STAGE(buf0, 0);
    __syncthreads();                        // drains vmcnt before barrier

    const int sw = (rlo & 7) << 4;

    for (int t = 0; t < 8; ++t) {
        float* cur = (t & 1) ? buf1 : buf0;
        float* nxt = (t & 1) ? buf0 : buf1;
        if (t < 7) STAGE(nxt, t + 1);       // overlaps compute below

        const char* xrow = (const char*)cur + rlo * 1024;
        f32x4 acc = (f32x4){0.f, 0.f, 0.f, 0.f};
#pragma unroll
        for (int kt = 0; kt < 8; ++kt) {
            const int L0 = kt * 128 + khi * 32;
            float4 a0 = *reinterpret_cast<const float4*>(xrow + (L0 ^ sw));
            float4 a1 = *reinterpret_cast<const float4*>(xrow + ((L0 + 16) ^ sw));
            float f0[8] = {a0.x, a0.y, a0.z, a0.w, a1.x, a1.y, a1.z, a1.w};
            bf16x8 ah, al;
#pragma unroll
            for (int j = 0; j < 8; ++j) {
                unsigned u = __float_as_uint(f0[j]);
                ah[j] = (short)(u >> 16);
                float r = f0[j] - __uint_as_float(u & 0xFFFF0000u);
                al[j] = (short)(__float_as_uint(r) >> 16);
            }
            acc = __builtin_amdgcn_mfma_f32_16x16x32_bf16(ah, FH[kt], acc, 0, 0, 0);
            acc = __builtin_amdgcn_mfma_f32_16x16x32_bf16(ah, FL[kt], acc, 0, 0, 0);
            acc = __builtin_amdgcn_mfma_f32_16x16x32_bf16(al, FH[kt], acc, 0, 0, 0);
        }
        // C/D: col = wid*16 + rlo, row = t*16 + khi*4 + i; store bf16 RTN
#pragma unroll
        for (int i = 0; i < 4; ++i) {
            int row = row0 + t * 16 + khi * 4 + i;
            if (row < N) {
                unsigned u = __float_as_uint(acc[i]);
                u += 0x7fffu + ((u >> 16) & 1u);
                xw[(size_t)row * OUT_DIM + wid * 16 + rlo] =
                    (unsigned short)(u >> 16);
            }
        }
        __syncthreads();   // nxt staged & everyone done reading cur
    }
}

// ---- K3: exclusive scan of bucket counts -----------------------------------
__global__ __launch_bounds__(1024) void scanb_k(const int* __restrict__ cnt,
                                                int* __restrict__ base,
                                                int* __restrict__ cursor,
                                                int NB, int E) {
    __shared__ int s[1024];
    int t = threadIdx.x;
    int v = (t < NB) ? cnt[t] : 0;
    s[t] = v;
    __syncthreads();
#pragma unroll
    for (int o = 1; o < 1024; o <<= 1) {
        int a = (t >= o) ? s[t - o] : 0;
        __syncthreads();
        s[t] += a;
        __syncthreads();
    }
    if (t < NB) { base[t] = s[t] - v; cursor[t] = s[t] - v; }
    if (t == 0) base[NB] = E;
}

// ---- K4: partition: rec[] grouped by bucket --------------------------------
// rec = { src | (dst&127)<<17 , bits(w) }; br = b<<19 | dlow<<12 | rank
__global__ __launch_bounds__(256) void part_k(const int* __restrict__ esrc,
                                              const int* __restrict__ edst,
                                              const float* __restrict__ ew,
                                              int* __restrict__ cursor,
                                              int2* __restrict__ rec,
                                              int E, int NB) {
    __shared__ int h[1024];
    __shared__ int bb[1024];
    int t = threadIdx.x;
#pragma unroll
    for (int i = t; i < 1024; i += 256) h[i] = 0;
    __syncthreads();
    const int e0 = blockIdx.x * (256 * IPT);
    int br[IPT];
#pragma unroll
    for (int i = 0; i < IPT; ++i) {
        int e = e0 + i * 256 + t;
        br[i] = -1;
        if (e < E) {
            int d = edst[e];
            int b = d >> 7;
            int r = atomicAdd(&h[b], 1);
            br[i] = (b << 19) | ((d & 127) << 12) | r;
        }
    }
    __syncthreads();
    for (int i = t; i < NB; i += 256) {
        int c = h[i];
        bb[i] = c ? atomicAdd(&cursor[i], c) : 0;
    }
    __syncthreads();
#pragma unroll
    for (int i = 0; i < IPT; ++i) {
        if (br[i] >= 0) {
            int e = e0 + i * 256 + t;
            int b = br[i] >> 19;
            int dlow = (br[i] >> 12) & 127;
            int r = br[i] & 0xFFF;
            rec[bb[b] + r] = make_int2(esrc[e] | (dlow << 17),
                                       __float_as_int(ew[e]));
        }
    }
}

// ---- K5: fused finalize+gather: sort bucket into LDS, gather, ReLU ---------
__global__ __launch_bounds__(256) void fingather_k(
        const unsigned short* __restrict__ xw,
        const int2* __restrict__ rec, const int* __restrict__ base,
        int2* __restrict__ valg,            // global fallback (rarely used)
        float* __restrict__ out, int N) {
    __shared__ int cnt_s[NPB];
    __shared__ int sc[NPB];
    __shared__ int cur_s[NPB];
    __shared__ int off_s[NPB + 1];
    __shared__ int2 val_s[CAP];             // 24KB
    const int t = threadIdx.x;
    const int b = blockIdx.x;
    const int s = base[b], e = base[b + 1];
    const bool fits = (e - s) <= CAP;

    if (t < NPB) cnt_s[t] = 0;
    __syncthreads();
    for (int i = s + t; i < e; i += 256)
        atomicAdd(&cnt_s[(rec[i].x >> 17) & 127], 1);
    __syncthreads();

    if (t < NPB) sc[t] = cnt_s[t];
    __syncthreads();
#pragma unroll
    for (int o = 1; o < NPB; o <<= 1) {
        int a = 0;
        if (t < NPB && t >= o) a = sc[t - o];
        __syncthreads();
        if (t < NPB) sc[t] += a;
        __syncthreads();
    }
    if (t < NPB) {
        cur_s[t] = sc[t] - cnt_s[t];
        off_s[t + 1] = sc[t];
    }
    if (t == 0) off_s[0] = 0;
    __syncthreads();

    if (fits) {
        for (int i = s + t; i < e; i += 256) {
            int2 r = rec[i];
            int slot = atomicAdd(&cur_s[(r.x >> 17) & 127], 1);
            val_s[slot] = make_int2(r.x & 0x1FFFF, r.y);
        }
    } else {
        for (int i = s + t; i < e; i += 256) {
            int2 r = rec[i];
            int slot = atomicAdd(&cur_s[(r.x >> 17) & 127], 1);
            valg[s + slot] = make_int2(r.x & 0x1FFFF, r.y);
        }
    }
    __syncthreads();

    const int lane = t & 63, wid = t >> 6;
    const int g = lane >> 3, sl = lane & 7;
    const int2* vp = fits ? val_s : (valg + s);

    for (int n = wid; n < NPB; n += 4) {
        const int node = b * NPB + n;
        if (node >= N) break;
        const int b0 = off_s[n], e0 = off_s[n + 1];
        float acc[8];
#pragma unroll
        for (int j = 0; j < 8; ++j) acc[j] = 0.f;

        for (int i = b0; i < e0; i += 16) {
            int idx0 = i + g;
            int idx1 = i + g + 8;
            int2 r0 = vp[min(idx0, e0 - 1)];
            int2 r1 = vp[min(idx1, e0 - 1)];
            float w0 = (idx0 < e0) ? __int_as_float(r0.y) : 0.f;
            float w1 = (idx1 < e0) ? __int_as_float(r1.y) : 0.f;
            int4 row0 = *reinterpret_cast<const int4*>(
                xw + (size_t)r0.x * OUT_DIM + sl * 8);
            int4 row1 = *reinterpret_cast<const int4*>(
                xw + (size_t)r1.x * OUT_DIM + sl * 8);
            unsigned a0 = (unsigned)row0.x, a1 = (unsigned)row0.y;
            unsigned a2 = (unsigned)row0.z, a3 = (unsigned)row0.w;
            acc[0] += w0 * __uint_as_float(a0 << 16);
            acc[1] += w0 * __uint_as_float(a0 & 0xFFFF0000u);
            acc[2] += w0 * __uint_as_float(a1 << 16);
            acc[3] += w0 * __uint_as_float(a1 & 0xFFFF0000u);
            acc[4] += w0 * __uint_as_float(a2 << 16);
            acc[5] += w0 * __uint_as_float(a2 & 0xFFFF0000u);
            acc[6] += w0 * __uint_as_float(a3 << 16);
            acc[7] += w0 * __uint_as_float(a3 & 0xFFFF0000u);
            unsigned c0 = (unsigned)row1.x, c1 = (unsigned)row1.y;
            unsigned c2 = (unsigned)row1.z, c3 = (unsigned)row1.w;
            acc[0] += w1 * __uint_as_float(c0 << 16);
            acc[1] += w1 * __uint_as_float(c0 & 0xFFFF0000u);
            acc[2] += w1 * __uint_as_float(c1 << 16);
            acc[3] += w1 * __uint_as_float(c1 & 0xFFFF0000u);
            acc[4] += w1 * __uint_as_float(c2 << 16);
            acc[5] += w1 * __uint_as_float(c2 & 0xFFFF0000u);
            acc[6] += w1 * __uint_as_float(c3 << 16);
            acc[7] += w1 * __uint_as_float(c3 & 0xFFFF0000u);
        }

#pragma unroll
        for (int m = 8; m < 64; m <<= 1)
#pragma unroll
            for (int j = 0; j < 8; ++j)
                acc[j] += __shfl_xor(acc[j], m);

        if (g == 0) {
            float4 v0 = make_float4(fmaxf(acc[0], 0.f), fmaxf(acc[1], 0.f),
                                    fmaxf(acc[2], 0.f), fmaxf(acc[3], 0.f));
            float4 v1 = make_float4(fmaxf(acc[4], 0.f), fmaxf(acc[5], 0.f),
                                    fmaxf(acc[6], 0.f), fmaxf(acc[7], 0.f));
            float4* op = reinterpret_cast<float4*>(
                out + (size_t)node * OUT_DIM + sl * 8);
            op[0] = v0;
            op[1] = v1;
        }
    }
}

extern "C" void kernel_launch(void* const* d_in, const int* in_sizes, int n_in,
                              void* d_out, int out_size, void* d_ws, size_t ws_size,
                              hipStream_t stream) {
    const float* x    = (const float*)d_in[0];
    const float* W    = (const float*)d_in[1];
    const int*   esrc = (const int*)d_in[2];
    const int*   edst = (const int*)d_in[3];
    const float* ew   = (const float*)d_in[4];
    float* out = (float*)d_out;

    const int N  = in_sizes[0] / IN_DIM;     // 100000
    const int E  = in_sizes[2];              // 1600000
    const int NB = (N + NPB - 1) / NPB;      // 782
    const int GB = (N + 127) / 128;          // gemm blocks = 782
    const int HB = 512;                      // histogram blocks
    const int PB = (E + 256 * IPT - 1) / (256 * IPT);   // 391

    char* ws = (char*)d_ws;
    size_t o = 0;
    bf16x8* fragH = (bf16x8*)(ws + o);  o += 32 * 64 * 16;
    bf16x8* fragL = (bf16x8*)(ws + o);  o += 32 * 64 * 16;
    unsigned short* xw = (unsigned short*)(ws + o);
    o += (size_t)N * OUT_DIM * 2;            // 12.8 MB
    int2* rec  = (int2*)(ws + o);       o += (size_t)E * 8;   // 12.8 MB
    int2* val  = (int2*)(ws + o);       o += (size_t)E * 8;   // fallback only
    int* cnt   = (int*)(ws + o);        o += 1024 * 4;
    int* base  = (int*)(ws + o);        o += 1025 * 4;
    int* cursor = (int*)(ws + o);       o += 1024 * 4;

    wfrag_k<<<32, 64, 0, stream>>>(W, fragH, fragL, cnt);
    gemm_hist_k<<<GB + HB, 256, 0, stream>>>(x, fragH, fragL, xw, edst, cnt,
                                             N, E, GB, HB);
    scanb_k<<<1, 1024, 0, stream>>>(cnt, base, cursor, NB, E);
    part_k<<<PB, 256, 0, stream>>>(esrc, edst, ew, cursor, rec, E, NB);
    fingather_k<<<NB, 256, 0, stream>>>(xw, rec, base, val, out, N);
}

// Round 12
// 123.979 us; speedup vs baseline: 1.1633x; 1.0307x over previous
//
#include <hip/hip_runtime.h>

constexpr int IN_DIM  = 256;
constexpr int OUT_DIM = 64;
constexpr int NPB     = 64;           // nodes per bucket (dst >> 6)
constexpr int NBK     = 2048;         // bucket array size (>= NB)
constexpr int IPT     = 16;           // edges per thread in part_k
constexpr int CAP     = 1280;         // LDS bucket capacity in fingather

typedef __attribute__((ext_vector_type(8))) short bf16x8;
typedef __attribute__((ext_vector_type(4))) float f32x4;

__device__ __forceinline__ void gload_lds16(const void* g, void* l) {
    __builtin_amdgcn_global_load_lds(
        (const __attribute__((address_space(1))) void*)g,
        (__attribute__((address_space(3))) void*)l, 16, 0, 0);
}

// ---- K1: W fragment precompute + zero cnt[] --------------------------------
__global__ __launch_bounds__(64) void wfrag_k(const float* __restrict__ W,
                                              bf16x8* __restrict__ fragH,
                                              bf16x8* __restrict__ fragL,
                                              int* __restrict__ cnt) {
    const int gid = blockIdx.x * 64 + threadIdx.x;   // 32*64 = 2048 exactly
    cnt[gid] = 0;

    const int kt = blockIdx.x >> 2;
    const int nt = blockIdx.x & 3;
    const int l  = threadIdx.x;
    const int col = nt * 16 + (l & 15);
    const int k0  = kt * 32 + (l >> 4) * 8;
    bf16x8 h, lo;
#pragma unroll
    for (int j = 0; j < 8; ++j) {
        float f = W[(size_t)(k0 + j) * OUT_DIM + col];
        unsigned u = __float_as_uint(f);
        h[j] = (short)(u >> 16);
        float r = f - __uint_as_float(u & 0xFFFF0000u);
        lo[j] = (short)(__float_as_uint(r) >> 16);
    }
    fragH[blockIdx.x * 64 + l] = h;
    fragL[blockIdx.x * 64 + l] = lo;
}

// ---- K2: union — [0,GB) = pipelined LDS GEMM, [GB,GB+HB) = histogram -------
__global__ __launch_bounds__(256, 4) void gemm_hist_k(
        const float* __restrict__ x,
        const bf16x8* __restrict__ fragH, const bf16x8* __restrict__ fragL,
        unsigned short* __restrict__ xw,
        const int* __restrict__ edst, int* __restrict__ cnt,
        int N, int E, int GB, int HB) {
    __shared__ char smem[32768];
    const int bid = blockIdx.x;
    const int tid = threadIdx.x;

    if (bid >= GB) {                        // ---- histogram role ----
        int* h = (int*)smem;                // [2048]
        for (int i = tid; i < NBK; i += 256) h[i] = 0;
        __syncthreads();
        const int hb = bid - GB;
        const int n4 = E >> 2;
        for (int i = hb * 256 + tid; i < n4; i += HB * 256) {
            int4 d4 = reinterpret_cast<const int4*>(edst)[i];
            atomicAdd(&h[d4.x >> 6], 1);
            atomicAdd(&h[d4.y >> 6], 1);
            atomicAdd(&h[d4.z >> 6], 1);
            atomicAdd(&h[d4.w >> 6], 1);
        }
        if (hb == 0)
            for (int e = (n4 << 2) + tid; e < E; e += 256)
                atomicAdd(&h[edst[e] >> 6], 1);
        __syncthreads();
        for (int i = tid; i < NBK; i += 256)
            if (h[i]) atomicAdd(&cnt[i], h[i]);
        return;
    }

    // ---- GEMM role: 128 rows/block, 8 tiles x 16 rows, dbuf 2x16KB ----
    const int lane = tid & 63;
    const int wid  = tid >> 6;
    const int row0 = bid * 128;
    const int rlo = lane & 15, khi = lane >> 4;

    bf16x8 FH[8], FL[8];
#pragma unroll
    for (int kt = 0; kt < 8; ++kt) {
        FH[kt] = fragH[(kt * 4 + wid) * 64 + lane];
        FL[kt] = fragL[(kt * 4 + wid) * 64 + lane];
    }

    float* buf0 = (float*)smem;
    float* buf1 = (float*)(smem + 16384);

    auto STAGE = [&](float* buf, int tile) {
#pragma unroll
        for (int i = 0; i < 4; ++i) {
            int rit = i * 4 + wid;
            int gr = row0 + tile * 16 + rit;
            if (gr > N - 1) gr = N - 1;
            int slot = lane ^ (rit & 7);
            gload_lds16(x + (size_t)gr * IN_DIM + slot * 4,
                        (char*)buf + rit * 1024);
        }
    };

    STAGE(buf0, 0);
    __syncthreads();

    const int sw = (rlo & 7) << 4;

    for (int t = 0; t < 8; ++t) {
        float* cur = (t & 1) ? buf1 : buf0;
        float* nxt = (t & 1) ? buf0 : buf1;
        if (t < 7) STAGE(nxt, t + 1);

        const char* xrow = (const char*)cur + rlo * 1024;
        f32x4 acc = (f32x4){0.f, 0.f, 0.f, 0.f};
#pragma unroll
        for (int kt = 0; kt < 8; ++kt) {
            const int L0 = kt * 128 + khi * 32;
            float4 a0 = *reinterpret_cast<const float4*>(xrow + (L0 ^ sw));
            float4 a1 = *reinterpret_cast<const float4*>(xrow + ((L0 + 16) ^ sw));
            float f0[8] = {a0.x, a0.y, a0.z, a0.w, a1.x, a1.y, a1.z, a1.w};
            bf16x8 ah, al;
#pragma unroll
            for (int j = 0; j < 8; ++j) {
                unsigned u = __float_as_uint(f0[j]);
                ah[j] = (short)(u >> 16);
                float r = f0[j] - __uint_as_float(u & 0xFFFF0000u);
                al[j] = (short)(__float_as_uint(r) >> 16);
            }
            acc = __builtin_amdgcn_mfma_f32_16x16x32_bf16(ah, FH[kt], acc, 0, 0, 0);
            acc = __builtin_amdgcn_mfma_f32_16x16x32_bf16(ah, FL[kt], acc, 0, 0, 0);
            acc = __builtin_amdgcn_mfma_f32_16x16x32_bf16(al, FH[kt], acc, 0, 0, 0);
        }
#pragma unroll
        for (int i = 0; i < 4; ++i) {
            int row = row0 + t * 16 + khi * 4 + i;
            if (row < N) {
                unsigned u = __float_as_uint(acc[i]);
                u += 0x7fffu + ((u >> 16) & 1u);
                xw[(size_t)row * OUT_DIM + wid * 16 + rlo] =
                    (unsigned short)(u >> 16);
            }
        }
        __syncthreads();
    }
}

// ---- K3: exclusive scan of NB (<=2048) bucket counts, one block ------------
__global__ __launch_bounds__(1024) void scanb_k(const int* __restrict__ cnt,
                                                int* __restrict__ base,
                                                int* __restrict__ cursor,
                                                int NB, int E) {
    __shared__ int s[1024];
    int t = threadIdx.x;
    int i0 = 2 * t, i1 = 2 * t + 1;
    int v0 = (i0 < NB) ? cnt[i0] : 0;
    int v1 = (i1 < NB) ? cnt[i1] : 0;
    s[t] = v0 + v1;
    __syncthreads();
#pragma unroll
    for (int o = 1; o < 1024; o <<= 1) {
        int a = (t >= o) ? s[t - o] : 0;
        __syncthreads();
        s[t] += a;
        __syncthreads();
    }
    int excl = s[t] - v0 - v1;
    if (i0 < NB) { base[i0] = excl;      cursor[i0] = excl; }
    if (i1 < NB) { base[i1] = excl + v0; cursor[i1] = excl + v0; }
    if (t == 0) base[NB] = E;
}

// ---- K4: partition: rec[] grouped by bucket --------------------------------
// rec = { src | (dst&63)<<17 , bits(w) }; br = b<<18 | dlow<<12 | rank
__global__ __launch_bounds__(256) void part_k(const int* __restrict__ esrc,
                                              const int* __restrict__ edst,
                                              const float* __restrict__ ew,
                                              int* __restrict__ cursor,
                                              int2* __restrict__ rec,
                                              int E, int NB) {
    __shared__ int h[NBK];
    __shared__ int bb[NBK];
    int t = threadIdx.x;
#pragma unroll
    for (int i = t; i < NBK; i += 256) h[i] = 0;
    __syncthreads();
    const int e0 = blockIdx.x * (256 * IPT);
    int br[IPT];
#pragma unroll
    for (int i = 0; i < IPT; ++i) {
        int e = e0 + i * 256 + t;
        br[i] = -1;
        if (e < E) {
            int d = edst[e];
            int b = d >> 6;
            int r = atomicAdd(&h[b], 1);     // local rank < 4096
            br[i] = (b << 18) | ((d & 63) << 12) | r;
        }
    }
    __syncthreads();
    for (int i = t; i < NB; i += 256) {
        int c = h[i];
        bb[i] = c ? atomicAdd(&cursor[i], c) : 0;
    }
    __syncthreads();
#pragma unroll
    for (int i = 0; i < IPT; ++i) {
        if (br[i] >= 0) {
            int e = e0 + i * 256 + t;
            int b = br[i] >> 18;
            int dlow = (br[i] >> 12) & 63;
            int r = br[i] & 0xFFF;
            rec[bb[b] + r] = make_int2(esrc[e] | (dlow << 17),
                                       __float_as_int(ew[e]));
        }
    }
}

// ---- K5: fused finalize+gather, NPB=64: sort bucket into LDS, gather, ReLU -
__global__ __launch_bounds__(256) void fingather_k(
        const unsigned short* __restrict__ xw,
        const int2* __restrict__ rec, const int* __restrict__ base,
        int2* __restrict__ valg,            // global fallback (stat. never)
        float* __restrict__ out, int N) {
    __shared__ int cnt_s[NPB];
    __shared__ int sc[NPB];
    __shared__ int cur_s[NPB];
    __shared__ int off_s[NPB + 1];
    __shared__ int2 val_s[CAP];             // 10KB
    const int t = threadIdx.x;
    const int b = blockIdx.x;
    const int s = base[b], e = base[b + 1];
    const bool fits = (e - s) <= CAP;

    if (t < NPB) cnt_s[t] = 0;
    __syncthreads();
    for (int i = s + t; i < e; i += 256)
        atomicAdd(&cnt_s[(rec[i].x >> 17) & 63], 1);
    __syncthreads();

    if (t < NPB) sc[t] = cnt_s[t];
    __syncthreads();
#pragma unroll
    for (int o = 1; o < NPB; o <<= 1) {
        int a = 0;
        if (t < NPB && t >= o) a = sc[t - o];
        __syncthreads();
        if (t < NPB) sc[t] += a;
        __syncthreads();
    }
    if (t < NPB) {
        cur_s[t] = sc[t] - cnt_s[t];
        off_s[t + 1] = sc[t];
    }
    if (t == 0) off_s[0] = 0;
    __syncthreads();

    if (fits) {
        for (int i = s + t; i < e; i += 256) {
            int2 r = rec[i];
            int slot = atomicAdd(&cur_s[(r.x >> 17) & 63], 1);
            val_s[slot] = make_int2(r.x & 0x1FFFF, r.y);
        }
    } else {
        for (int i = s + t; i < e; i += 256) {
            int2 r = rec[i];
            int slot = atomicAdd(&cur_s[(r.x >> 17) & 63], 1);
            valg[s + slot] = make_int2(r.x & 0x1FFFF, r.y);
        }
    }
    __syncthreads();

    const int lane = t & 63, wid = t >> 6;
    const int g = lane >> 3, sl = lane & 7;
    const int2* vp = fits ? val_s : (valg + s);

    for (int n = wid; n < NPB; n += 4) {
        const int node = b * NPB + n;
        if (node >= N) break;
        const int b0 = off_s[n], e0 = off_s[n + 1];
        float acc[8];
#pragma unroll
        for (int j = 0; j < 8; ++j) acc[j] = 0.f;

        for (int i = b0; i < e0; i += 32) {  // 32 edges in flight
            int idx0 = i + g;
            int idx1 = i + g + 8;
            int idx2 = i + g + 16;
            int idx3 = i + g + 24;
            int2 r0 = vp[min(idx0, e0 - 1)];
            int2 r1 = vp[min(idx1, e0 - 1)];
            int2 r2 = vp[min(idx2, e0 - 1)];
            int2 r3 = vp[min(idx3, e0 - 1)];
            float w0 = (idx0 < e0) ? __int_as_float(r0.y) : 0.f;
            float w1 = (idx1 < e0) ? __int_as_float(r1.y) : 0.f;
            float w2 = (idx2 < e0) ? __int_as_float(r2.y) : 0.f;
            float w3 = (idx3 < e0) ? __int_as_float(r3.y) : 0.f;
            int4 q0 = *reinterpret_cast<const int4*>(
                xw + (size_t)r0.x * OUT_DIM + sl * 8);
            int4 q1 = *reinterpret_cast<const int4*>(
                xw + (size_t)r1.x * OUT_DIM + sl * 8);
            int4 q2 = *reinterpret_cast<const int4*>(
                xw + (size_t)r2.x * OUT_DIM + sl * 8);
            int4 q3 = *reinterpret_cast<const int4*>(
                xw + (size_t)r3.x * OUT_DIM + sl * 8);
#define ACCUM(Q, W)                                                   \
            {                                                         \
                unsigned u0 = (unsigned)Q.x, u1 = (unsigned)Q.y;      \
                unsigned u2 = (unsigned)Q.z, u3 = (unsigned)Q.w;      \
                acc[0] += W * __uint_as_float(u0 << 16);              \
                acc[1] += W * __uint_as_float(u0 & 0xFFFF0000u);      \
                acc[2] += W * __uint_as_float(u1 << 16);              \
                acc[3] += W * __uint_as_float(u1 & 0xFFFF0000u);      \
                acc[4] += W * __uint_as_float(u2 << 16);              \
                acc[5] += W * __uint_as_float(u2 & 0xFFFF0000u);      \
                acc[6] += W * __uint_as_float(u3 << 16);              \
                acc[7] += W * __uint_as_float(u3 & 0xFFFF0000u);      \
            }
            ACCUM(q0, w0)
            ACCUM(q1, w1)
            ACCUM(q2, w2)
            ACCUM(q3, w3)
#undef ACCUM
        }

#pragma unroll
        for (int m = 8; m < 64; m <<= 1)
#pragma unroll
            for (int j = 0; j < 8; ++j)
                acc[j] += __shfl_xor(acc[j], m);

        if (g == 0) {
            float4 v0 = make_float4(fmaxf(acc[0], 0.f), fmaxf(acc[1], 0.f),
                                    fmaxf(acc[2], 0.f), fmaxf(acc[3], 0.f));
            float4 v1 = make_float4(fmaxf(acc[4], 0.f), fmaxf(acc[5], 0.f),
                                    fmaxf(acc[6], 0.f), fmaxf(acc[7], 0.f));
            float4* op = reinterpret_cast<float4*>(
                out + (size_t)node * OUT_DIM + sl * 8);
            op[0] = v0;
            op[1] = v1;
        }
    }
}

extern "C" void kernel_launch(void* const* d_in, const int* in_sizes, int n_in,
                              void* d_out, int out_size, void* d_ws, size_t ws_size,
                              hipStream_t stream) {
    const float* x    = (const float*)d_in[0];
    const float* W    = (const float*)d_in[1];
    const int*   esrc = (const int*)d_in[2];
    const int*   edst = (const int*)d_in[3];
    const float* ew   = (const float*)d_in[4];
    float* out = (float*)d_out;

    const int N  = in_sizes[0] / IN_DIM;     // 100000
    const int E  = in_sizes[2];              // 1600000
    const int NB = (N + NPB - 1) / NPB;      // 1563
    const int GB = (N + 127) / 128;          // gemm blocks = 782
    const int HB = 512;                      // histogram blocks
    const int PB = (E + 256 * IPT - 1) / (256 * IPT);   // 391

    char* ws = (char*)d_ws;
    size_t o = 0;
    bf16x8* fragH = (bf16x8*)(ws + o);  o += 32 * 64 * 16;
    bf16x8* fragL = (bf16x8*)(ws + o);  o += 32 * 64 * 16;
    unsigned short* xw = (unsigned short*)(ws + o);
    o += (size_t)N * OUT_DIM * 2;            // 12.8 MB
    int2* rec  = (int2*)(ws + o);       o += (size_t)E * 8;   // 12.8 MB
    int2* val  = (int2*)(ws + o);       o += (size_t)E * 8;   // fallback only
    int* cnt   = (int*)(ws + o);        o += NBK * 4;
    int* base  = (int*)(ws + o);        o += (NBK + 1) * 4;
    int* cursor = (int*)(ws + o);       o += NBK * 4;

    wfrag_k<<<32, 64, 0, stream>>>(W, fragH, fragL, cnt);
    gemm_hist_k<<<GB + HB, 256, 0, stream>>>(x, fragH, fragL, xw, edst, cnt,
                                             N, E, GB, HB);
    scanb_k<<<1, 1024, 0, stream>>>(cnt, base, cursor, NB, E);
    part_k<<<PB, 256, 0, stream>>>(esrc, edst, ew, cursor, rec, E, NB);
    fingather_k<<<NB, 256, 0, stream>>>(xw, rec, base, val, out, N);
}